// Round 1
// baseline (485.853 us; speedup 1.0000x reference)
//
#include <hip/hip_runtime.h>

// Problem: x[B,C,H,W] fp32, percents[B] fp32.
// lengths[b] = (int)(W * percents[b]); out[b,c,h,w] = (w >= lengths[b]) ? 0 : x[...]
// B=16, C=64, H=80, W=1024.

constexpr int kB = 16;
constexpr int kC = 64;
constexpr int kH = 80;
constexpr int kW = 1024;
constexpr int kVecPerRow = kW / 4;  // 256 == blockDim.x: one block per (b,c,h) row

__global__ __launch_bounds__(256) void mask_cnn_kernel(
    const float4* __restrict__ x, const float* __restrict__ percents,
    float4* __restrict__ out) {
    // grid: (C*H, B). Each block handles one W-row of 256 float4s.
    const int b = blockIdx.y;
    const int row = blockIdx.x;                       // c*H + h
    const long long vec_idx =
        ((long long)b * (kC * kH) + row) * kVecPerRow + threadIdx.x;
    const int w4 = threadIdx.x * 4;                   // first W position of this float4

    // Match jnp: (W * percents).astype(int32) -> fp32 multiply, truncate.
    const int len = (int)((float)kW * percents[b]);   // wave-uniform scalar load

    if (w4 + 4 <= len) {
        // fully live
        out[vec_idx] = x[vec_idx];
    } else if (w4 >= len) {
        // fully masked: skip the read entirely
        out[vec_idx] = make_float4(0.f, 0.f, 0.f, 0.f);
    } else {
        // straddles the boundary (at most one float4 per row)
        float4 v = x[vec_idx];
        if (w4 + 0 >= len) v.x = 0.f;
        if (w4 + 1 >= len) v.y = 0.f;
        if (w4 + 2 >= len) v.z = 0.f;
        if (w4 + 3 >= len) v.w = 0.f;
        out[vec_idx] = v;
    }
}

extern "C" void kernel_launch(void* const* d_in, const int* in_sizes, int n_in,
                              void* d_out, int out_size, void* d_ws, size_t ws_size,
                              hipStream_t stream) {
    const float4* x = (const float4*)d_in[0];
    const float* percents = (const float*)d_in[1];
    float4* out = (float4*)d_out;

    dim3 grid(kC * kH, kB);   // 5120 x 16 blocks
    dim3 block(256);
    mask_cnn_kernel<<<grid, block, 0, stream>>>(x, percents, out);
}